// Round 8
// baseline (163.372 us; speedup 1.0000x reference)
//
#include <hip/hip_runtime.h>

// B=2, N=2048, DIM=768, HEADS=12, HD=64, SCALE=1/8
#define BATCH 2
#define SEQ   2048
#define DIMC  768
#define HEADS 12
#define HD    64
#define SCALE 0.125f

typedef short bf16x8 __attribute__((ext_vector_type(8)));
typedef float f32x16 __attribute__((ext_vector_type(16)));

__device__ __forceinline__ unsigned short f2bf(float f) {
    union { float f; unsigned int u; } a; a.f = f;
    unsigned int r = a.u + 0x7fffu + ((a.u >> 16) & 1u);
    return (unsigned short)(r >> 16);
}
__device__ __forceinline__ unsigned int pack2bf(float lo, float hi) {
    union { float f; unsigned int u; } a, b; a.f = lo; b.f = hi;
    return __builtin_amdgcn_perm(b.u + 0x8000u, a.u + 0x8000u, 0x07060302);
}

// ---- fused prep: x->bf16 (8/thread) + coalesced 32x32-tile transposes ----
#define PB_XB   1536     // 1536*256*8 = 3,145,728 = 4096*768
#define PB_WQ   576
#define PB_WKV  96
#define PB_WPR  576
__global__ void prep(const float* __restrict__ x, const float* __restrict__ Wq,
                     const float* __restrict__ Wkv, const float* __restrict__ Wproj,
                     unsigned short* __restrict__ xb, unsigned short* __restrict__ WqT,
                     unsigned short* __restrict__ WkvT, unsigned short* __restrict__ WprT)
{
    const int bid = blockIdx.x, t = threadIdx.x;
    if (bid < PB_XB) {
        int id = bid * 256 + t;
        float4 v0 = ((const float4*)x)[id * 2];
        float4 v1 = ((const float4*)x)[id * 2 + 1];
        uint4 o = { pack2bf(v0.x, v0.y), pack2bf(v0.z, v0.w),
                    pack2bf(v1.x, v1.y), pack2bf(v1.z, v1.w) };
        ((uint4*)xb)[id] = o;
        return;
    }
    __shared__ float sT[32][33];
    const float* W; unsigned short* WT; int N, tb;
    if (bid < PB_XB + PB_WQ)               { W = Wq;    WT = WqT;  N = DIMC;   tb = bid - PB_XB; }
    else if (bid < PB_XB + PB_WQ + PB_WKV) { W = Wkv;   WT = WkvT; N = 2 * HD; tb = bid - PB_XB - PB_WQ; }
    else                                   { W = Wproj; WT = WprT; N = DIMC;   tb = bid - PB_XB - PB_WQ - PB_WKV; }
    const int tilesN = N / 32;
    const int k0 = (tb / tilesN) * 32, n0 = (tb - (tb / tilesN) * tilesN) * 32;
    const int r = t >> 3, c4 = (t & 7) * 4;
    float4 v = *(const float4*)&W[(size_t)(k0 + r) * N + n0 + c4];
    sT[c4 + 0][r] = v.x; sT[c4 + 1][r] = v.y; sT[c4 + 2][r] = v.z; sT[c4 + 3][r] = v.w;
    __syncthreads();
    ushort4 o = { f2bf(sT[r][c4]), f2bf(sT[r][c4 + 1]), f2bf(sT[r][c4 + 2]), f2bf(sT[r][c4 + 3]) };
    *(ushort4*)&WT[(size_t)(n0 + r) * 768 + k0 + c4] = o;
}

// ---- MFMA GEMM, 64(M)x128(N) C-tile, 8 waves (each one 32x32 subtile),
// BK=64 (4 MFMA per wave per barrier), double-buffered LDS (1 barrier/ki).
// MODE 0: fused QKV (BT=[WqT;WkvT], 896 rows): n<768 -> Qw bf16 * SCALE,
//         n>=768 -> K [tok][64] / VT [b][d][tok]. MODE 1: fp32 + bias.
template <int MODE>
__global__ __launch_bounds__(512, 4)
void gemm64(const unsigned short* __restrict__ A, const unsigned short* __restrict__ BT,
            const float* __restrict__ bias, void* __restrict__ C0,
            unsigned short* __restrict__ Kout, unsigned short* __restrict__ VTout)
{
    __shared__ __align__(16) unsigned short sA[2][64][72];
    __shared__ __align__(16) unsigned short sB[2][128][72];
    const int t = threadIdx.x, lane = t & 63, w = t >> 6;
    const int l31 = lane & 31, hi = lane >> 5;
    const int mh = w >> 2, nq = w & 3;
    const int bm = blockIdx.y * 64, bn = blockIdx.x * 128;

    const int ta = t & 255;
    const bool doA = t < 256;
    const int ar = ta >> 2, ac = (ta & 3) * 16;   // A: 64x64, 2 b128/thread
    const int br = ta >> 1, bc = (ta & 1) * 32;   // B: 128x64, 4 b128/thread
    const unsigned short* Ap = &A [(size_t)(bm + ar) * 768 + ac];
    const unsigned short* Bp = &BT[(size_t)(bn + br) * 768 + bc];

    if (doA) {
        *(bf16x8*)&sA[0][ar][ac]     = *(const bf16x8*)&Ap[0];
        *(bf16x8*)&sA[0][ar][ac + 8] = *(const bf16x8*)&Ap[8];
    } else {
        *(bf16x8*)&sB[0][br][bc]      = *(const bf16x8*)&Bp[0];
        *(bf16x8*)&sB[0][br][bc + 8]  = *(const bf16x8*)&Bp[8];
        *(bf16x8*)&sB[0][br][bc + 16] = *(const bf16x8*)&Bp[16];
        *(bf16x8*)&sB[0][br][bc + 24] = *(const bf16x8*)&Bp[24];
    }
    __syncthreads();

    f32x16 acc = {};
    for (int ki = 0; ki < 12; ++ki) {
        const int buf = ki & 1;
        if (ki + 1 < 12) {
            const int ko = (ki + 1) * 64;
            if (doA) {
                *(bf16x8*)&sA[buf ^ 1][ar][ac]     = *(const bf16x8*)&Ap[ko];
                *(bf16x8*)&sA[buf ^ 1][ar][ac + 8] = *(const bf16x8*)&Ap[ko + 8];
            } else {
                *(bf16x8*)&sB[buf ^ 1][br][bc]      = *(const bf16x8*)&Bp[ko];
                *(bf16x8*)&sB[buf ^ 1][br][bc + 8]  = *(const bf16x8*)&Bp[ko + 8];
                *(bf16x8*)&sB[buf ^ 1][br][bc + 16] = *(const bf16x8*)&Bp[ko + 16];
                *(bf16x8*)&sB[buf ^ 1][br][bc + 24] = *(const bf16x8*)&Bp[ko + 24];
            }
        }
        #pragma unroll
        for (int s = 0; s < 4; ++s) {
            bf16x8 a = *(const bf16x8*)&sA[buf][mh * 32 + l31][s * 16 + hi * 8];
            bf16x8 b = *(const bf16x8*)&sB[buf][nq * 32 + l31][s * 16 + hi * 8];
            acc = __builtin_amdgcn_mfma_f32_32x32x16_bf16(a, b, acc, 0, 0, 0);
        }
        __syncthreads();
    }

    const int n = bn + nq * 32 + l31;
    #pragma unroll
    for (int r = 0; r < 16; ++r) {
        const int m = bm + mh * 32 + (r & 3) + 8 * (r >> 2) + 4 * hi;
        float val = acc[r];
        if (MODE == 0) {
            if (n < 768) {
                ((unsigned short*)C0)[(size_t)m * 768 + n] = f2bf(val * SCALE);
            } else {
                int c2 = n - 768;
                if (c2 < HD) Kout[(size_t)m * HD + c2] = f2bf(val);
                else {
                    int bb = m >> 11, tok = m & (SEQ - 1);
                    VTout[(size_t)bb * HD * SEQ + (size_t)(c2 - HD) * SEQ + tok] = f2bf(val);
                }
            }
        } else {
            ((float*)C0)[(size_t)m * 768 + n] = val + bias[n];
        }
    }
}

// ---- MFMA flash attention, 8 waves, in-block 2-way key split.
// Wave = (g = even/odd kt tile, kr = key half, qc = query half).
// 16 supersteps; each stages 2 K-tiles + 2 V-tiles (512 thr, single-buffered,
// 2 barriers/superstep). No-max softmax (exact by shift-invariance; |S|<~10).
// Epilogue: combine g (32KB LDS scratch), then kr (16KB), divide by l.
__global__ __launch_bounds__(512, 6)
void flash_kernel(const unsigned short* __restrict__ Qw, const unsigned short* __restrict__ Kw,
                  const unsigned short* __restrict__ VTw, unsigned short* __restrict__ Ob)
{
    const int qblk = blockIdx.x, h = blockIdx.y, b = blockIdx.z;
    const int tid = threadIdx.x, w = tid >> 6, lane = tid & 63;
    const int l31 = lane & 31, hi = lane >> 5;
    const int g = w >> 2, kr = (w >> 1) & 1, qc = w & 1;

    // flat LDS: K tiles [g][64][72] at 0, VT tiles [g][64][72] at 9216
    __shared__ __align__(16) unsigned short sMem[2 * 9216];
    __shared__ float sL[8][32];
    __shared__ float sLi[2][32];
#define SKa(gg,r,c)  sMem[((gg) * 64 + (r)) * 72 + (c)]
#define SVTa(gg,r,c) sMem[9216 + ((gg) * 64 + (r)) * 72 + (c)]

    const size_t qrow = (size_t)(b * SEQ + qblk * 64 + qc * 32 + l31);
    bf16x8 qf[4];
    #pragma unroll
    for (int s = 0; s < 4; ++s)
        qf[s] = *(const bf16x8*)&Qw[qrow * DIMC + h * HD + s * 16 + hi * 8];

    f32x16 oacc0 = {}, oacc1 = {};   // d 0..31 / 32..63
    float lsum = 0.0f;

    const int r_st = tid >> 3, c_st = (tid & 7) * 8;   // 64x64 tile, 1 b128/thread/tile
    const unsigned short* Kp  = &Kw[(size_t)(b * SEQ + r_st) * HD + c_st];
    const unsigned short* VTp = &VTw[(size_t)b * HD * SEQ + (size_t)r_st * SEQ + c_st];

    for (int ss = 0; ss < 16; ++ss) {
        // stage tiles 2ss (g=0) and 2ss+1 (g=1): 4 b128 per thread
        const unsigned short* k0 = Kp + (size_t)(2 * ss) * 64 * HD;
        const unsigned short* v0 = VTp + 2 * ss * 64;
        *(bf16x8*)&SKa(0, r_st, c_st)  = *(const bf16x8*)&k0[0];
        *(bf16x8*)&SKa(1, r_st, c_st)  = *(const bf16x8*)&k0[64 * HD];
        *(bf16x8*)&SVTa(0, r_st, c_st) = *(const bf16x8*)&v0[0];
        *(bf16x8*)&SVTa(1, r_st, c_st) = *(const bf16x8*)&v0[64];
        __syncthreads();

        // S^T = K·Q^T for this wave's (g, kr): 4 chained k-steps over d
        f32x16 st = {};
        #pragma unroll
        for (int s = 0; s < 4; ++s) {
            bf16x8 ka = *(const bf16x8*)&SKa(g, kr * 32 + l31, s * 16 + hi * 8);
            st = __builtin_amdgcn_mfma_f32_32x32x16_bf16(ka, qf[s], st, 0, 0, 0);
        }

        // p = exp(s), accumulate l, pack. C rows: key = (r&3)+8*(r>>2)+4*hi
        uint2 pg[4];
        #pragma unroll
        for (int gg = 0; gg < 4; ++gg) {
            float p0 = __expf(st[gg * 4 + 0]);
            float p1 = __expf(st[gg * 4 + 1]);
            float p2 = __expf(st[gg * 4 + 2]);
            float p3 = __expf(st[gg * 4 + 3]);
            lsum += (p0 + p1) + (p2 + p3);
            pg[gg].x = pack2bf(p0, p1);
            pg[gg].y = pack2bf(p2, p3);
        }

        // C-layout -> A-layout via one shfl_xor(32) exchange; PV
        #pragma unroll
        for (int s = 0; s < 2; ++s) {
            uint2 send; send.x = hi ? pg[2 * s].x : pg[2 * s + 1].x;
                        send.y = hi ? pg[2 * s].y : pg[2 * s + 1].y;
            uint2 recv; recv.x = __shfl_xor((int)send.x, 32);
                        recv.y = __shfl_xor((int)send.y, 32);
            union { uint4 u; bf16x8 v; } pa;
            pa.u.x = hi ? recv.x : pg[2 * s].x;
            pa.u.y = hi ? recv.y : pg[2 * s].y;
            pa.u.z = hi ? pg[2 * s + 1].x : recv.x;
            pa.u.w = hi ? pg[2 * s + 1].y : recv.y;
            bf16x8 vb0 = *(const bf16x8*)&SVTa(g, l31,      kr * 32 + s * 16 + hi * 8);
            bf16x8 vb1 = *(const bf16x8*)&SVTa(g, 32 + l31, kr * 32 + s * 16 + hi * 8);
            oacc0 = __builtin_amdgcn_mfma_f32_32x32x16_bf16(pa.v, vb0, oacc0, 0, 0, 0);
            oacc1 = __builtin_amdgcn_mfma_f32_32x32x16_bf16(pa.v, vb1, oacc1, 0, 0, 0);
        }
        __syncthreads();
    }

    // ---- epilogue ----
    lsum += __shfl_xor(lsum, 32);            // wave's 32-key quarter, per q=l31
    if (lane < 32) sL[w][l31] = lsum;

    float* scratch = (float*)sMem;           // 36.8 KB region, staging dead
    // E1: group 1 gives both d-tiles to its (kr,qc) twin
    if (g == 1) {
        const int slot = (w & 3) * 2048;
        #pragma unroll
        for (int r = 0; r < 16; ++r) {
            scratch[slot + r * 64 + lane]        = oacc0[r];
            scratch[slot + 1024 + r * 64 + lane] = oacc1[r];
        }
    }
    __syncthreads();
    // E2: group 0 absorbs
    if (g == 0) {
        const int slot = w * 2048;
        #pragma unroll
        for (int r = 0; r < 16; ++r) {
            oacc0[r] += scratch[slot + r * 64 + lane];
            oacc1[r] += scratch[slot + 1024 + r * 64 + lane];
        }
    }
    __syncthreads();
    // E3: kr-exchange among group-0 waves: give away non-owned d-tile
    if (g == 0) {
        const int rid = qc * 2 + (1 - kr);
        f32x16 give = kr ? oacc0 : oacc1;
        #pragma unroll
        for (int r = 0; r < 16; ++r) scratch[rid * 1024 + r * 64 + lane] = give[r];
    }
    __syncthreads();
    // E4: absorb partner tile; compute 1/l
    f32x16 own = kr ? oacc1 : oacc0;
    if (g == 0) {
        const float* rg = scratch + (qc * 2 + kr) * 1024;
        #pragma unroll
        for (int r = 0; r < 16; ++r) own[r] += rg[r * 64 + lane];
        if (kr == 0 && lane < 32)
            sLi[qc][l31] = 1.0f / (sL[qc][l31] + sL[2 + qc][l31] + sL[4 + qc][l31] + sL[6 + qc][l31]);
    }
    __syncthreads();
    if (g == 0) {
        #pragma unroll
        for (int r = 0; r < 16; ++r) {
            int rq = (r & 3) + 8 * (r >> 2) + 4 * hi;
            float iv = sLi[qc][rq];
            size_t row = (size_t)(b * SEQ + qblk * 64 + qc * 32 + rq);
            Ob[row * DIMC + h * HD + kr * 32 + l31] = f2bf(own[r] * iv);
        }
    }
#undef SKa
#undef SVTa
}

extern "C" void kernel_launch(void* const* d_in, const int* in_sizes, int n_in,
                              void* d_out, int out_size, void* d_ws, size_t ws_size,
                              hipStream_t stream)
{
    const float* x     = (const float*)d_in[0];
    const float* Wq    = (const float*)d_in[1];
    const float* Wkv   = (const float*)d_in[2];
    const float* Wproj = (const float*)d_in[3];
    const float* bproj = (const float*)d_in[4];

    const int M = BATCH * SEQ;               // 4096
    unsigned short* xb   = (unsigned short*)d_ws;           // 4096*768
    unsigned short* WqT  = xb   + (size_t)M * DIMC;         // 768*768   } contiguous
    unsigned short* WkvT = WqT  + DIMC * DIMC;              // 128*768   } [896][768]
    unsigned short* WprT = WkvT + 2 * HD * DIMC;            // 768*768
    unsigned short* Qw   = WprT + DIMC * DIMC;              // 4096*768 (pre-scaled)
    unsigned short* Kw   = Qw   + (size_t)M * DIMC;         // 4096*64
    unsigned short* VTw  = Kw   + (size_t)M * HD;           // 2*64*2048
    unsigned short* Ob   = VTw  + (size_t)BATCH * HD * SEQ; // 4096*768

    prep<<<PB_XB + PB_WQ + PB_WKV + PB_WPR, 256, 0, stream>>>(
        x, Wq, Wkv, Wproj, xb, WqT, WkvT, WprT);

    // fused QKV: [Q | K V] = x @ [WqT;WkvT]^T   (448 blocks x 512 thr)
    gemm64<0><<<dim3(7, M / 64), 512, 0, stream>>>(xb, WqT, nullptr, Qw, Kw, VTw);
    // flash attention -> Ob  (768 blocks x 512 thr)
    flash_kernel<<<dim3(SEQ / 64, HEADS, BATCH), 512, 0, stream>>>(Qw, Kw, VTw, Ob);
    // out = Ob @ Wproj + bias (fp32)   (384 blocks x 512 thr)
    gemm64<1><<<dim3(6, M / 64), 512, 0, stream>>>(Ob, WprT, bproj, d_out, nullptr, nullptr);
}